// Round 9
// baseline (138.539 us; speedup 1.0000x reference)
//
#include <hip/hip_runtime.h>
#include <hip/hip_bf16.h>

typedef unsigned short u16;
typedef unsigned int u32;

#define AS1 __attribute__((address_space(1)))
#define AS3 __attribute__((address_space(3)))

typedef __attribute__((ext_vector_type(8))) __bf16 bf16x8;
typedef __attribute__((ext_vector_type(4))) float f32x4;
typedef __attribute__((ext_vector_type(8))) u16 u16x8;

static __device__ __forceinline__ u16 f2bf(float f) {
    u32 x = __builtin_bit_cast(u32, f);
    u32 r = (x + 0x7fffu + ((x >> 16) & 1u)) >> 16;
    return (u16)r;
}
static __device__ __forceinline__ float bf2f(u16 u) {
    u32 x = ((u32)u) << 16;
    return __builtin_bit_cast(float, x);
}
static __device__ __forceinline__ void gload_lds16(const void* g, void* l) {
    __builtin_amdgcn_global_load_lds((const AS1 u32*)g, (AS3 u32*)l, 16, 0, 0);
}
static __device__ __forceinline__ u32 cvtpk(float lo, float hi) {
    u32 r;
    asm("v_cvt_pk_bf16_f32 %0, %1, %2" : "=v"(r) : "v"(lo), "v"(hi));
    return r;
}

// ---------------- cast X (fp32 -> bf16), 8 elems/thread ----------------
__global__ __launch_bounds__(256) void k_cast_bf16(const float* __restrict__ in,
                                                   u16* __restrict__ out, int n8) {
    int i = blockIdx.x * 256 + threadIdx.x;
    if (i >= n8) return;
    typedef __attribute__((ext_vector_type(4))) float fx4;
    const fx4* p = (const fx4*)in;
    fx4 a = p[2 * i], b = p[2 * i + 1];
    u16x8 o;
    o[0] = f2bf(a[0]); o[1] = f2bf(a[1]); o[2] = f2bf(a[2]); o[3] = f2bf(a[3]);
    o[4] = f2bf(b[0]); o[5] = f2bf(b[1]); o[6] = f2bf(b[2]); o[7] = f2bf(b[3]);
    *(u16x8*)(out + (size_t)i * 8) = o;
}

// ------------- transpose + cast W: [K,N] fp32 -> [N,K] bf16 -------------
__global__ __launch_bounds__(256) void k_wtrans(const float* __restrict__ W,
                                                u16* __restrict__ Wt, int K_, int N_) {
    __shared__ u16 T[64][65];
    int nt = blockIdx.x, kt = blockIdx.y;
    int t = threadIdx.x, c = t & 63, r0 = t >> 6;
#pragma unroll
    for (int i = 0; i < 16; i++) {
        int k = r0 + i * 4;
        T[k][c] = f2bf(W[(size_t)(kt * 64 + k) * N_ + nt * 64 + c]);
    }
    __syncthreads();
#pragma unroll
    for (int i = 0; i < 16; i++) {
        int nn = r0 + i * 4;
        Wt[(size_t)(nt * 64 + nn) * K_ + kt * 64 + c] = T[c][nn];
    }
}

// ---------------- bf16 MFMA GEMM (128^2, 2-phase): A[M,K] x Bt[N,K]^T ----------------
// EPI=0: fp32 out, direct coalesced stores. EPI=1: QKV scatter via LDS-transpose
// full-line epilogue (R8-proven pattern; static acc indices per rule #20).
template <int EPI>
__global__ __launch_bounds__(256, 2) void k_gemm(
    const u16* __restrict__ A, const u16* __restrict__ Bt,
    const float* __restrict__ bias, float* __restrict__ outf,
    u16* __restrict__ Qb, u16* __restrict__ Kb, u16* __restrict__ Vb,
    int Msz, int Nsz, int Ksz) {
    __shared__ u16 Al[128 * 64];
    __shared__ u16 Bl[128 * 64];
    int tid = threadIdx.x;
    int m0 = blockIdx.x * 128, n0 = blockIdx.y * 128;
    int w = tid >> 6, lane = tid & 63, l15 = lane & 15, lg = lane >> 4;
    int wr = (w >> 1) * 64, wc = (w & 1) * 64;
    f32x4 acc[4][4] = {};

    for (int k0 = 0; k0 < Ksz; k0 += 64) {
#pragma unroll
        for (int i = 0; i < 4; i++) {
            int c = i * 256 + tid;
            gload_lds16(A + (size_t)(m0 + (c >> 3)) * Ksz + k0 + (c & 7) * 8,
                        &Al[(c & ~63) * 8]);
        }
#pragma unroll
        for (int i = 0; i < 4; i++) {
            int c = i * 256 + tid;
            gload_lds16(Bt + (size_t)(n0 + (c >> 3)) * Ksz + k0 + (c & 7) * 8,
                        &Bl[(c & ~63) * 8]);
        }
        __syncthreads();
#pragma unroll
        for (int kk = 0; kk < 2; kk++) {
            bf16x8 af[4], bfr[4];
#pragma unroll
            for (int m = 0; m < 4; m++)
                af[m] = *(const bf16x8*)&Al[(wr + m * 16 + l15) * 64 + kk * 32 + lg * 8];
#pragma unroll
            for (int n = 0; n < 4; n++)
                bfr[n] = *(const bf16x8*)&Bl[(wc + n * 16 + l15) * 64 + kk * 32 + lg * 8];
#pragma unroll
            for (int m = 0; m < 4; m++)
#pragma unroll
                for (int n = 0; n < 4; n++)
                    acc[m][n] = __builtin_amdgcn_mfma_f32_16x16x32_bf16(af[m], bfr[n], acc[m][n], 0, 0, 0);
        }
        __syncthreads();
    }

    if (EPI == 0) {
#pragma unroll
        for (int n = 0; n < 4; n++) {
            int gn = n0 + wc + n * 16 + l15;
            float bv = bias[gn];
#pragma unroll
            for (int m = 0; m < 4; m++) {
                int gmb = m0 + wr + m * 16 + lg * 4;
#pragma unroll
                for (int r = 0; r < 4; r++)
                    outf[(size_t)(gmb + r) * Nsz + gn] = acc[m][n][r] + bv;
            }
        }
    } else {
        // ---- coalesced scatter: acc -> LDS bf16 [32][136] -> full-line stores ----
        u16* T = Al;
        const int TP = 136;
        float bv[4];
#pragma unroll
        for (int n = 0; n < 4; n++) bv[n] = bias[n0 + wc + n * 16 + l15];
        int lrow = tid >> 3;           // 0..31
        int c0 = (tid & 7) << 4;       // 0..112
        int gcol = n0 + c0;
        int which = gcol >> 10, d = gcol & 1023, h = d >> 6, dd = d & 63;
        u16* dstb = which == 0 ? Qb : (which == 1 ? Kb : Vb);

#define EPI_CHUNK(mc)                                                              \
    {                                                                              \
        __syncthreads();                                                           \
        if (((mc) >> 1) == (w >> 1)) {                                             \
            _Pragma("unroll") for (int n = 0; n < 4; n++) {                        \
                _Pragma("unroll") for (int r = 0; r < 4; r++) {                    \
                    int lr = (lg << 2) + r;                                        \
                    T[lr * TP + wc + (n << 4) + l15] =                             \
                        f2bf(acc[2 * ((mc) & 1)][n][r] + bv[n]);                   \
                    T[(16 + lr) * TP + wc + (n << 4) + l15] =                      \
                        f2bf(acc[2 * ((mc) & 1) + 1][n][r] + bv[n]);               \
                }                                                                  \
            }                                                                      \
        }                                                                          \
        __syncthreads();                                                           \
        int gm = m0 + (mc) * 32 + lrow;                                            \
        int b = gm >> 10, s = gm & 1023;                                           \
        u16* dp = dstb + ((size_t)(b * 16 + h) * 1024 + s) * 64 + dd;              \
        const u16* sp = &T[lrow * TP + c0];                                        \
        *(u16x8*)dp = *(const u16x8*)sp;                                           \
        *(u16x8*)(dp + 8) = *(const u16x8*)(sp + 8);                               \
    }

        EPI_CHUNK(0) EPI_CHUNK(1) EPI_CHUNK(2) EPI_CHUNK(3)
#undef EPI_CHUNK
    }
}

// -- V transpose: [bh][S][64] -> [bh][64][S], + per-tile column partial sums --
__global__ __launch_bounds__(256) void k_vtrans(const u16* __restrict__ Vb,
                                                u16* __restrict__ Vt,
                                                float* __restrict__ vpart) {
    __shared__ u16 T[64][65];
    __shared__ float red[4][64];
    int st = blockIdx.x, bh = blockIdx.y;
    int t = threadIdx.x, c = t & 63, r0 = t >> 6;
    const u16* Vh = Vb + (size_t)bh * 65536;
    u16* Vth = Vt + (size_t)bh * 65536;
    float a = 0.f;
#pragma unroll
    for (int i = 0; i < 16; i++) {
        int s = r0 + i * 4;
        u16 v = Vh[(size_t)(st * 64 + s) * 64 + c];
        T[s][c] = v;
        a += bf2f(v);
    }
    red[r0][c] = a;
    __syncthreads();
#pragma unroll
    for (int i = 0; i < 16; i++) {
        int d = r0 + i * 4;
        Vth[(size_t)d * 1024 + st * 64 + c] = T[c][d];
    }
    if (r0 == 0)
        vpart[((size_t)bh * 16 + st) * 64 + c] =
            red[0][c] + red[1][c] + red[2][c] + red[3][c];
}

// ---------------- vsum2: reduce 16 tile-partials per (bh,d) ----------------
__global__ __launch_bounds__(256) void k_vsum2(const float* __restrict__ vpart,
                                               float* __restrict__ vsum) {
    int idx = blockIdx.x * 256 + threadIdx.x;  // idx = bh*64 + d
    int bh = idx >> 6, d = idx & 63;
    const float* p = vpart + (size_t)bh * 1024 + d;
    float s = 0.f;
#pragma unroll
    for (int st = 0; st < 16; st++) s += p[st * 64];
    vsum[idx] = s;
}

// ---- attention v3: LDS-staged K/V (dbuf), swapped-QK^T, 8 waves x 16 rows ----
__global__ __launch_bounds__(512, 4) void k_attn(const u16* __restrict__ Qb,
                                                 const u16* __restrict__ Kb,
                                                 const u16* __restrict__ Vt,
                                                 const float* __restrict__ vsum,
                                                 u16* __restrict__ ctx) {
    __shared__ u16 Kl[2][4096];   // [64 k-rows][128B], swizzled
    __shared__ u16 Vl[2][4096];   // [64 d-rows][128B], swizzled
    __shared__ u16 Pl[8 * 1024];  // 2KB per wave
    __shared__ float rsw[8][16];
    int tid = threadIdx.x, w = tid >> 6, lane = tid & 63, l15 = lane & 15, lg = lane >> 4;
    int p = blockIdx.x;
    int tb = 7 - (p >> 6);        // heavy blocks dispatch first
    int bh = p & 63;              // bh%8 == p%8 -> all 8 blocks of a bh on one XCD
    int qb = tb * 128 + w * 16;
    int nkb = 2 * tb + 2;
    int klast = (qb + 15) >> 6;   // last k-block this wave participates in

    const u16* Qh = Qb + (size_t)bh * 65536;
    const u16* Kh = Kb + (size_t)bh * 65536;
    const u16* Vh = Vt + (size_t)bh * 65536;
    u16* Pw = &Pl[w * 1024];
    int swz = (l15 & 7) << 4;
    int q = qb + l15;

    bf16x8 qf[2];
#pragma unroll
    for (int kk = 0; kk < 2; kk++)
        qf[kk] = *(const bf16x8*)(Qh + (size_t)q * 64 + kk * 32 + lg * 8);
    float vs[4];
#pragma unroll
    for (int n = 0; n < 4; n++) vs[n] = vsum[bh * 64 + n * 16 + l15];

    int srow = tid >> 3, schunk = tid & 7;
    int soff = ((schunk * 16) ^ ((srow & 7) << 4)) >> 1;  // elems within row
    u16* kdst = &Kl[0][0] + w * 512;
    u16* vdst = &Vl[0][0] + w * 512;

    f32x4 ctxa[4] = {};
    float rsp = 0.f;
    int cur = 0;

    gload_lds16(Kh + (size_t)srow * 64 + soff, kdst);
    gload_lds16(Vh + (size_t)srow * 1024 + soff, vdst);
    __syncthreads();

    for (int kb = 0; kb < nkb; kb++) {
        if (kb + 1 < nkb) {
            int nx = cur ^ 1;
            gload_lds16(Kh + (size_t)(((kb + 1) << 6) + srow) * 64 + soff,
                        &Kl[nx][0] + w * 512);
            gload_lds16(Vh + (size_t)srow * 1024 + ((kb + 1) << 6) + soff,
                        &Vl[nx][0] + w * 512);
        }
        if (kb <= klast) {
            bool masked = (kb == klast);
            const char* Kc = (const char*)&Kl[cur][0];
            const char* Vc = (const char*)&Vl[cur][0];
            f32x4 sc[4] = {};
#pragma unroll
            for (int kk = 0; kk < 2; kk++)
#pragma unroll
                for (int n = 0; n < 4; n++) {
                    bf16x8 kf = *(const bf16x8*)(Kc + ((((n * 16 + l15) << 7) + (kk << 6) + (lg << 4)) ^ swz));
                    sc[n] = __builtin_amdgcn_mfma_f32_16x16x32_bf16(kf, qf[kk], sc[n], 0, 0, 0);
                }
            int qml = q - (kb << 6) - (lg << 2);
#pragma unroll
            for (int n = 0; n < 4; n++) {
                float v0 = fmaxf(sc[n][0] * 0.125f, 0.f);
                float v1 = fmaxf(sc[n][1] * 0.125f, 0.f);
                float v2 = fmaxf(sc[n][2] * 0.125f, 0.f);
                float v3 = fmaxf(sc[n][3] * 0.125f, 0.f);
                if (masked) {
                    int c = qml - n * 16;
                    v0 = (0 <= c) ? v0 : 0.f;
                    v1 = (1 <= c) ? v1 : 0.f;
                    v2 = (2 <= c) ? v2 : 0.f;
                    v3 = (3 <= c) ? v3 : 0.f;
                }
                rsp += (v0 + v1) + (v2 + v3);
                u32 w0 = cvtpk(v0, v1), w1 = cvtpk(v2, v3);
                int base = l15 * 128 + n * 32 + lg * 8;
                *(u32*)((char*)Pw + ((base) ^ swz)) = w0;
                *(u32*)((char*)Pw + ((base + 4) ^ swz)) = w1;
            }
            bf16x8 pf0 = *(const bf16x8*)((char*)Pw + ((l15 * 128 + lg * 16) ^ swz));
            bf16x8 pf1 = *(const bf16x8*)((char*)Pw + ((l15 * 128 + 64 + lg * 16) ^ swz));
#pragma unroll
            for (int n = 0; n < 4; n++) {
                bf16x8 vf = *(const bf16x8*)(Vc + ((((n * 16 + l15) << 7) + (lg << 4)) ^ swz));
                ctxa[n] = __builtin_amdgcn_mfma_f32_16x16x32_bf16(pf0, vf, ctxa[n], 0, 0, 0);
            }
#pragma unroll
            for (int n = 0; n < 4; n++) {
                bf16x8 vf = *(const bf16x8*)(Vc + ((((n * 16 + l15) << 7) + 64 + (lg << 4)) ^ swz));
                ctxa[n] = __builtin_amdgcn_mfma_f32_16x16x32_bf16(pf1, vf, ctxa[n], 0, 0, 0);
            }
        }
        __syncthreads();
        cur ^= 1;
    }

    float tsum = rsp;
    tsum += __shfl_xor(tsum, 16);
    tsum += __shfl_xor(tsum, 32);
    rsw[w][l15] = tsum;
    f32x4 rv = *(f32x4*)&rsw[w][lg * 4];
    const float EPS = 1e-12f, EPSN = 1e-12f / 1024.f;
    float inv[4];
#pragma unroll
    for (int r = 0; r < 4; r++) inv[r] = 1.f / (rv[r] + EPS);
    int b = bh >> 4, h = bh & 15;
#pragma unroll
    for (int n = 0; n < 4; n++) {
#pragma unroll
        for (int r = 0; r < 4; r++) {
            int qq = qb + lg * 4 + r;
            float val = (ctxa[n][r] + EPSN * vs[n]) * inv[r];
            ctx[(size_t)(b * 1024 + qq) * 1024 + h * 64 + n * 16 + l15] = f2bf(val);
        }
    }
}

// ----- fp32 fixup GEMM: q,k rows s<16 of each (b,h) exactly from fp32 X,W -----
__global__ __launch_bounds__(256) void k_qkfix(const float* __restrict__ X,
                                               const float* __restrict__ W,
                                               const float* __restrict__ bias,
                                               float* __restrict__ Qf,
                                               float* __restrict__ Kf) {
    __shared__ float red[4][8][64];
    int cb = blockIdx.x;
    int b = blockIdx.y >> 1, rh = blockIdx.y & 1;
    int tid = threadIdx.x, w = tid >> 6, lane = tid & 63;
    int col = cb * 64 + lane;

    const float* Wp = W + (size_t)(w * 256) * 3072 + col;
    const float* Xp = X + ((size_t)b * 1024 + rh * 8) * 1024 + w * 256;
    float acc[8] = {};
#pragma unroll 8
    for (int it = 0; it < 256; ++it) {
        float wv = Wp[(size_t)it * 3072];
#pragma unroll
        for (int j = 0; j < 8; j++) acc[j] += Xp[(size_t)j * 1024 + it] * wv;
    }
#pragma unroll
    for (int j = 0; j < 8; j++) red[w][j][lane] = acc[j];
    __syncthreads();

    int isK = cb >> 4, h = cb & 15;
    float* dst = isK ? Kf : Qf;
#pragma unroll
    for (int o = tid; o < 512; o += 256) {
        int j = o >> 6, c = o & 63;
        float s = red[0][j][c] + red[1][j][c] + red[2][j][c] + red[3][j][c];
        dst[((size_t)(b * 16 + h) * 16 + rh * 8 + j) * 64 + c] = s + bias[cb * 64 + c];
    }
}

// ----- fp32 fixup attention for rows q<16 of each head -----
__global__ __launch_bounds__(256) void k_attnfix(const float* __restrict__ Qf,
                                                 const float* __restrict__ Kf,
                                                 const u16* __restrict__ Vb,
                                                 const float* __restrict__ vsum,
                                                 u16* __restrict__ ctx) {
    __shared__ float ps[16][17];
    __shared__ float dens[16];
    int bh = blockIdx.x, t = threadIdx.x;
    int q = t >> 4, k = t & 15;
    const float* Qr = Qf + ((size_t)bh * 16 + q) * 64;
    const float* Kr = Kf + ((size_t)bh * 16 + k) * 64;
    float s = 0.f;
    for (int d = 0; d < 64; d++) s += Qr[d] * Kr[d];
    s *= 0.125f;
    float p = (k <= q) ? fmaxf(s, 0.f) : 0.f;
    float den = p;
    den += __shfl_xor(den, 1); den += __shfl_xor(den, 2);
    den += __shfl_xor(den, 4); den += __shfl_xor(den, 8);
    ps[q][k] = p;
    if (k == 0) dens[q] = den;
    __syncthreads();
    int d0 = (t & 15) * 4;
    float c[4] = {};
    for (int kk = 0; kk <= q; kk++) {
        float pv = ps[q][kk];
        const u16* vr = Vb + ((size_t)bh * 1024 + kk) * 64 + d0;
        c[0] += pv * bf2f(vr[0]); c[1] += pv * bf2f(vr[1]);
        c[2] += pv * bf2f(vr[2]); c[3] += pv * bf2f(vr[3]);
    }
    float inv = 1.f / (dens[q] + 1e-12f);
    const float EPSN = 1e-12f / 1024.f;
    const float* vs = vsum + bh * 64 + d0;
    int b = bh >> 4, h = bh & 15;
    u16* dst = ctx + (size_t)(b * 1024 + q) * 1024 + h * 64 + d0;
#pragma unroll
    for (int j = 0; j < 4; j++) dst[j] = f2bf((c[j] + EPSN * vs[j]) * inv);
}

extern "C" void kernel_launch(void* const* d_in, const int* in_sizes, int n_in,
                              void* d_out, int out_size, void* d_ws, size_t ws_size,
                              hipStream_t stream) {
    const float* X = (const float*)d_in[0];
    const float* Wqkv = (const float*)d_in[1];
    const float* bqkv = (const float*)d_in[2];
    const float* Wproj = (const float*)d_in[3];
    const float* bproj = (const float*)d_in[4];
    float* out = (float*)d_out;
    char* ws = (char*)d_ws;

    u16* Xb     = (u16*)(ws);
    u16* Wqkvt  = (u16*)(ws + 8388608);
    u16* Wprojt = (u16*)(ws + 14680064);
    u16* Qb     = (u16*)(ws + 16777216);
    u16* Kb     = (u16*)(ws + 25165824);
    u16* Vb     = (u16*)(ws + 33554432);
    u16* Vt     = (u16*)(ws + 41943040);
    float* vsum = (float*)(ws + 50331648);   // 16 KB
    float* Qf   = (float*)(ws + 50348032);   // 256 KB
    float* Kf   = (float*)(ws + 50610176);   // 256 KB
    float* vpart= (float*)(ws + 50872320);   // 256 KB
    u16* ctx    = Xb;  // Xb dead after GEMM1; reuse for ctx

    k_cast_bf16<<<dim3(2048), dim3(256), 0, stream>>>(X, Xb, 524288);
    k_wtrans<<<dim3(48, 16), dim3(256), 0, stream>>>(Wqkv, Wqkvt, 1024, 3072);
    k_wtrans<<<dim3(16, 16), dim3(256), 0, stream>>>(Wproj, Wprojt, 1024, 1024);
    k_gemm<1><<<dim3(32, 24), dim3(256), 0, stream>>>(Xb, Wqkvt, bqkv, nullptr,
                                                      Qb, Kb, Vb, 4096, 3072, 1024);
    k_vtrans<<<dim3(16, 64), dim3(256), 0, stream>>>(Vb, Vt, vpart);
    k_vsum2<<<dim3(16), dim3(256), 0, stream>>>(vpart, vsum);
    k_qkfix<<<dim3(32, 8), dim3(256), 0, stream>>>(X, Wqkv, bqkv, Qf, Kf);
    k_attn<<<dim3(512), dim3(512), 0, stream>>>(Qb, Kb, Vt, vsum, ctx);
    k_attnfix<<<dim3(64), dim3(256), 0, stream>>>(Qf, Kf, Vb, vsum, ctx);
    k_gemm<0><<<dim3(32, 8), dim3(256), 0, stream>>>(ctx, Wprojt, bproj, out,
                                                     nullptr, nullptr, nullptr, 4096, 1024, 1024);
}

// Round 10
// 127.233 us; speedup vs baseline: 1.0889x; 1.0889x over previous
//
#include <hip/hip_runtime.h>
#include <hip/hip_bf16.h>

typedef unsigned short u16;
typedef unsigned int u32;

#define AS1 __attribute__((address_space(1)))
#define AS3 __attribute__((address_space(3)))

typedef __attribute__((ext_vector_type(8))) __bf16 bf16x8;
typedef __attribute__((ext_vector_type(4))) float f32x4;
typedef __attribute__((ext_vector_type(8))) u16 u16x8;

static __device__ __forceinline__ u16 f2bf(float f) {
    u32 x = __builtin_bit_cast(u32, f);
    u32 r = (x + 0x7fffu + ((x >> 16) & 1u)) >> 16;
    return (u16)r;
}
static __device__ __forceinline__ float bf2f(u16 u) {
    u32 x = ((u32)u) << 16;
    return __builtin_bit_cast(float, x);
}
static __device__ __forceinline__ void gload_lds16(const void* g, void* l) {
    __builtin_amdgcn_global_load_lds((const AS1 u32*)g, (AS3 u32*)l, 16, 0, 0);
}
static __device__ __forceinline__ u32 cvtpk(float lo, float hi) {
    u32 r;
    asm("v_cvt_pk_bf16_f32 %0, %1, %2" : "=v"(r) : "v"(lo), "v"(hi));
    return r;
}

// ---- prep: fused X cast (blocks 0..2047) + Wqkv trans (2048..2815) + Wproj trans ----
__global__ __launch_bounds__(256) void k_prep(const float* __restrict__ X,
                                              u16* __restrict__ Xb,
                                              const float* __restrict__ Wqkv,
                                              u16* __restrict__ Wqkvt,
                                              const float* __restrict__ Wproj,
                                              u16* __restrict__ Wprojt) {
    __shared__ u16 T[64][65];
    int bid = blockIdx.x, t = threadIdx.x;
    if (bid < 2048) {
        int i = bid * 256 + t;
        typedef __attribute__((ext_vector_type(4))) float fx4;
        const fx4* p = (const fx4*)X;
        fx4 a = p[2 * i], b = p[2 * i + 1];
        u16x8 o;
        o[0] = f2bf(a[0]); o[1] = f2bf(a[1]); o[2] = f2bf(a[2]); o[3] = f2bf(a[3]);
        o[4] = f2bf(b[0]); o[5] = f2bf(b[1]); o[6] = f2bf(b[2]); o[7] = f2bf(b[3]);
        *(u16x8*)(Xb + (size_t)i * 8) = o;
        return;
    }
    const float* W; u16* Wt; int N_, nt, kt;
    if (bid < 2816) {
        W = Wqkv; Wt = Wqkvt; N_ = 3072;
        int u = bid - 2048; nt = u % 48; kt = u / 48;
    } else {
        W = Wproj; Wt = Wprojt; N_ = 1024;
        int u = bid - 2816; nt = u & 15; kt = u >> 4;
    }
    int c = t & 63, r0 = t >> 6;
#pragma unroll
    for (int i = 0; i < 16; i++) {
        int k = r0 + i * 4;
        T[k][c] = f2bf(W[(size_t)(kt * 64 + k) * N_ + nt * 64 + c]);
    }
    __syncthreads();
#pragma unroll
    for (int i = 0; i < 16; i++) {
        int nn = r0 + i * 4;
        Wt[(size_t)(nt * 64 + nn) * 1024 + kt * 64 + c] = T[c][nn];
    }
}

// ---------------- bf16 MFMA GEMM (128^2, 2-phase): A[M,K] x Bt[N,K]^T ----------------
// EPI=1: QKV scatter; V-blocks write Vt (transposed) + vpart directly (vtrans fused),
// Vb only rows s<32 (attnfix needs s<16). All acc indices static (rule #20).
template <int EPI>
__global__ __launch_bounds__(256, 2) void k_gemm(
    const u16* __restrict__ A, const u16* __restrict__ Bt,
    const float* __restrict__ bias, float* __restrict__ outf,
    u16* __restrict__ Qb, u16* __restrict__ Kb, u16* __restrict__ Vb,
    u16* __restrict__ Vt, float* __restrict__ vpart,
    int Msz, int Nsz, int Ksz) {
    __shared__ u16 Al[128 * 64];
    __shared__ u16 Bl[128 * 64];
    int tid = threadIdx.x;
    int m0 = blockIdx.x * 128, n0 = blockIdx.y * 128;
    int w = tid >> 6, lane = tid & 63, l15 = lane & 15, lg = lane >> 4;
    int wr = (w >> 1) * 64, wc = (w & 1) * 64;
    f32x4 acc[4][4] = {};

    for (int k0 = 0; k0 < Ksz; k0 += 64) {
#pragma unroll
        for (int i = 0; i < 4; i++) {
            int c = i * 256 + tid;
            gload_lds16(A + (size_t)(m0 + (c >> 3)) * Ksz + k0 + (c & 7) * 8,
                        &Al[(c & ~63) * 8]);
        }
#pragma unroll
        for (int i = 0; i < 4; i++) {
            int c = i * 256 + tid;
            gload_lds16(Bt + (size_t)(n0 + (c >> 3)) * Ksz + k0 + (c & 7) * 8,
                        &Bl[(c & ~63) * 8]);
        }
        __syncthreads();
#pragma unroll
        for (int kk = 0; kk < 2; kk++) {
            bf16x8 af[4], bfr[4];
#pragma unroll
            for (int m = 0; m < 4; m++)
                af[m] = *(const bf16x8*)&Al[(wr + m * 16 + l15) * 64 + kk * 32 + lg * 8];
#pragma unroll
            for (int n = 0; n < 4; n++)
                bfr[n] = *(const bf16x8*)&Bl[(wc + n * 16 + l15) * 64 + kk * 32 + lg * 8];
#pragma unroll
            for (int m = 0; m < 4; m++)
#pragma unroll
                for (int n = 0; n < 4; n++)
                    acc[m][n] = __builtin_amdgcn_mfma_f32_16x16x32_bf16(af[m], bfr[n], acc[m][n], 0, 0, 0);
        }
        __syncthreads();
    }

    if (EPI == 0) {
#pragma unroll
        for (int n = 0; n < 4; n++) {
            int gn = n0 + wc + n * 16 + l15;
            float bv = bias[gn];
#pragma unroll
            for (int m = 0; m < 4; m++) {
                int gmb = m0 + wr + m * 16 + lg * 4;
#pragma unroll
                for (int r = 0; r < 4; r++)
                    outf[(size_t)(gmb + r) * Nsz + gn] = acc[m][n][r] + bv;
            }
        }
    } else {
        u16* T = Al;
        const int TP = 136;
        float bv[4];
#pragma unroll
        for (int n = 0; n < 4; n++) bv[n] = bias[n0 + wc + n * 16 + l15];
        int lrow = tid >> 3;           // 0..31
        int c0 = (tid & 7) << 4;       // 0..112
        int gcol = n0 + c0;
        int which = gcol >> 10, d = gcol & 1023, h = d >> 6, dd = d & 63;
        u16* dstb = which == 0 ? Qb : (which == 1 ? Kb : Vb);
        bool isV = (n0 >= 2048);
        int s0 = m0 & 1023, bq = m0 >> 10;
        int dl = tid >> 1, sh = tid & 1;  // V path: column dl 0..127, half sh
        int bhV = bq * 16 + ((n0 - 2048) >> 6) + (dl >> 6);
        float vp0 = 0.f, vp1 = 0.f;

#define EPI_CHUNK(mc)                                                              \
    {                                                                              \
        __syncthreads();                                                           \
        if (((mc) >> 1) == (w >> 1)) {                                             \
            _Pragma("unroll") for (int n = 0; n < 4; n++) {                        \
                _Pragma("unroll") for (int r = 0; r < 4; r++) {                    \
                    int lr = (lg << 2) + r;                                        \
                    T[lr * TP + wc + (n << 4) + l15] =                             \
                        f2bf(acc[2 * ((mc) & 1)][n][r] + bv[n]);                   \
                    T[(16 + lr) * TP + wc + (n << 4) + l15] =                      \
                        f2bf(acc[2 * ((mc) & 1) + 1][n][r] + bv[n]);               \
                }                                                                  \
            }                                                                      \
        }                                                                          \
        __syncthreads();                                                           \
        if (!isV) {                                                                \
            int gm = m0 + (mc) * 32 + lrow;                                        \
            int b = gm >> 10, s = gm & 1023;                                       \
            u16* dp = dstb + ((size_t)(b * 16 + h) * 1024 + s) * 64 + dd;          \
            const u16* sp = &T[lrow * TP + c0];                                    \
            *(u16x8*)dp = *(const u16x8*)sp;                                       \
            *(u16x8*)(dp + 8) = *(const u16x8*)(sp + 8);                           \
        } else {                                                                   \
            if ((mc) == 0 && s0 == 0) {                                            \
                u16* dp = dstb + ((size_t)(bq * 16 + h) * 1024 + lrow) * 64 + dd;  \
                const u16* sp = &T[lrow * TP + c0];                                \
                *(u16x8*)dp = *(const u16x8*)sp;                                   \
                *(u16x8*)(dp + 8) = *(const u16x8*)(sp + 8);                       \
            }                                                                      \
            float vls = 0.f;                                                       \
            u16x8 o0, o1;                                                          \
            _Pragma("unroll") for (int r = 0; r < 8; r++) {                        \
                u16 v = T[((sh << 4) + r) * TP + dl];                              \
                o0[r] = v; vls += bf2f(v);                                         \
            }                                                                      \
            _Pragma("unroll") for (int r = 0; r < 8; r++) {                        \
                u16 v = T[((sh << 4) + 8 + r) * TP + dl];                          \
                o1[r] = v; vls += bf2f(v);                                         \
            }                                                                      \
            vls += __shfl_xor(vls, 1);                                             \
            if ((mc) < 2) vp0 += vls; else vp1 += vls;                             \
            u16* vtp = Vt + (size_t)bhV * 65536 + (size_t)(dl & 63) * 1024 +       \
                       s0 + (mc) * 32 + (sh << 4);                                 \
            *(u16x8*)vtp = o0;                                                     \
            *(u16x8*)(vtp + 8) = o1;                                               \
        }                                                                          \
    }

        EPI_CHUNK(0) EPI_CHUNK(1) EPI_CHUNK(2) EPI_CHUNK(3)
#undef EPI_CHUNK

        if (isV && sh == 0) {
            int st0 = s0 >> 6;
            vpart[((size_t)bhV * 16 + st0) * 64 + (dl & 63)] = vp0;
            vpart[((size_t)bhV * 16 + st0 + 1) * 64 + (dl & 63)] = vp1;
        }
    }
}

// ---------- proj GEMM: 128x64 tiles (512 blocks, 2/CU), fp32 out ----------
__global__ __launch_bounds__(256, 2) void k_gemmP(
    const u16* __restrict__ A, const u16* __restrict__ Bt,
    const float* __restrict__ bias, float* __restrict__ outf) {
    __shared__ u16 Al[128 * 64];
    __shared__ u16 Bl[64 * 64];
    int tid = threadIdx.x;
    int m0 = blockIdx.x * 128, n0 = blockIdx.y * 64;
    int w = tid >> 6, lane = tid & 63, l15 = lane & 15, lg = lane >> 4;
    int wr = (w >> 1) * 64, wc = (w & 1) * 32;
    f32x4 acc[4][2] = {};

    for (int k0 = 0; k0 < 1024; k0 += 64) {
#pragma unroll
        for (int i = 0; i < 4; i++) {
            int c = i * 256 + tid;
            gload_lds16(A + (size_t)(m0 + (c >> 3)) * 1024 + k0 + (c & 7) * 8,
                        &Al[(c & ~63) * 8]);
        }
#pragma unroll
        for (int i = 0; i < 2; i++) {
            int c = i * 256 + tid;
            gload_lds16(Bt + (size_t)(n0 + (c >> 3)) * 1024 + k0 + (c & 7) * 8,
                        &Bl[(c & ~63) * 8]);
        }
        __syncthreads();
#pragma unroll
        for (int kk = 0; kk < 2; kk++) {
            bf16x8 af[4], bfr[2];
#pragma unroll
            for (int m = 0; m < 4; m++)
                af[m] = *(const bf16x8*)&Al[(wr + m * 16 + l15) * 64 + kk * 32 + lg * 8];
#pragma unroll
            for (int n = 0; n < 2; n++)
                bfr[n] = *(const bf16x8*)&Bl[(wc + n * 16 + l15) * 64 + kk * 32 + lg * 8];
#pragma unroll
            for (int m = 0; m < 4; m++)
#pragma unroll
                for (int n = 0; n < 2; n++)
                    acc[m][n] = __builtin_amdgcn_mfma_f32_16x16x32_bf16(af[m], bfr[n], acc[m][n], 0, 0, 0);
        }
        __syncthreads();
    }
#pragma unroll
    for (int n = 0; n < 2; n++) {
        int gn = n0 + wc + n * 16 + l15;
        float bv = bias[gn];
#pragma unroll
        for (int m = 0; m < 4; m++) {
            int gmb = m0 + wr + m * 16 + lg * 4;
#pragma unroll
            for (int r = 0; r < 4; r++)
                outf[(size_t)(gmb + r) * 1024 + gn] = acc[m][n][r] + bv;
        }
    }
}

// ---------------- vsum2: reduce 16 tile-partials per (bh,d) ----------------
__global__ __launch_bounds__(256) void k_vsum2(const float* __restrict__ vpart,
                                               float* __restrict__ vsum) {
    int idx = blockIdx.x * 256 + threadIdx.x;  // idx = bh*64 + d
    int bh = idx >> 6, d = idx & 63;
    const float* p = vpart + (size_t)bh * 1024 + d;
    float s = 0.f;
#pragma unroll
    for (int st = 0; st < 16; st++) s += p[st * 64];
    vsum[idx] = s;
}

// ---- attention v3: LDS-staged K/V (dbuf), swapped-QK^T, 8 waves x 16 rows ----
__global__ __launch_bounds__(512, 4) void k_attn(const u16* __restrict__ Qb,
                                                 const u16* __restrict__ Kb,
                                                 const u16* __restrict__ Vt,
                                                 const float* __restrict__ vsum,
                                                 u16* __restrict__ ctx) {
    __shared__ u16 Kl[2][4096];   // [64 k-rows][128B], swizzled
    __shared__ u16 Vl[2][4096];   // [64 d-rows][128B], swizzled
    __shared__ u16 Pl[8 * 1024];  // 2KB per wave
    __shared__ float rsw[8][16];
    int tid = threadIdx.x, w = tid >> 6, lane = tid & 63, l15 = lane & 15, lg = lane >> 4;
    int p = blockIdx.x;
    int tb = 7 - (p >> 6);        // heavy blocks dispatch first
    int bh = p & 63;              // bh%8 == p%8 -> all 8 blocks of a bh on one XCD
    int qb = tb * 128 + w * 16;
    int nkb = 2 * tb + 2;
    int klast = (qb + 15) >> 6;   // last k-block this wave participates in

    const u16* Qh = Qb + (size_t)bh * 65536;
    const u16* Kh = Kb + (size_t)bh * 65536;
    const u16* Vh = Vt + (size_t)bh * 65536;
    u16* Pw = &Pl[w * 1024];
    int swz = (l15 & 7) << 4;
    int q = qb + l15;

    bf16x8 qf[2];
#pragma unroll
    for (int kk = 0; kk < 2; kk++)
        qf[kk] = *(const bf16x8*)(Qh + (size_t)q * 64 + kk * 32 + lg * 8);
    float vs[4];
#pragma unroll
    for (int n = 0; n < 4; n++) vs[n] = vsum[bh * 64 + n * 16 + l15];

    int srow = tid >> 3, schunk = tid & 7;
    int soff = ((schunk * 16) ^ ((srow & 7) << 4)) >> 1;  // elems within row
    u16* kdst = &Kl[0][0] + w * 512;
    u16* vdst = &Vl[0][0] + w * 512;

    f32x4 ctxa[4] = {};
    float rsp = 0.f;
    int cur = 0;

    gload_lds16(Kh + (size_t)srow * 64 + soff, kdst);
    gload_lds16(Vh + (size_t)srow * 1024 + soff, vdst);
    __syncthreads();

    for (int kb = 0; kb < nkb; kb++) {
        if (kb + 1 < nkb) {
            int nx = cur ^ 1;
            gload_lds16(Kh + (size_t)(((kb + 1) << 6) + srow) * 64 + soff,
                        &Kl[nx][0] + w * 512);
            gload_lds16(Vh + (size_t)srow * 1024 + ((kb + 1) << 6) + soff,
                        &Vl[nx][0] + w * 512);
        }
        if (kb <= klast) {
            bool masked = (kb == klast);
            const char* Kc = (const char*)&Kl[cur][0];
            const char* Vc = (const char*)&Vl[cur][0];
            f32x4 sc[4] = {};
            __builtin_amdgcn_s_setprio(1);
#pragma unroll
            for (int kk = 0; kk < 2; kk++)
#pragma unroll
                for (int n = 0; n < 4; n++) {
                    bf16x8 kf = *(const bf16x8*)(Kc + ((((n * 16 + l15) << 7) + (kk << 6) + (lg << 4)) ^ swz));
                    sc[n] = __builtin_amdgcn_mfma_f32_16x16x32_bf16(kf, qf[kk], sc[n], 0, 0, 0);
                }
            __builtin_amdgcn_s_setprio(0);
            int qml = q - (kb << 6) - (lg << 2);
#pragma unroll
            for (int n = 0; n < 4; n++) {
                float v0 = fmaxf(sc[n][0] * 0.125f, 0.f);
                float v1 = fmaxf(sc[n][1] * 0.125f, 0.f);
                float v2 = fmaxf(sc[n][2] * 0.125f, 0.f);
                float v3 = fmaxf(sc[n][3] * 0.125f, 0.f);
                if (masked) {
                    int c = qml - n * 16;
                    v0 = (0 <= c) ? v0 : 0.f;
                    v1 = (1 <= c) ? v1 : 0.f;
                    v2 = (2 <= c) ? v2 : 0.f;
                    v3 = (3 <= c) ? v3 : 0.f;
                }
                rsp += (v0 + v1) + (v2 + v3);
                u32 w0 = cvtpk(v0, v1), w1 = cvtpk(v2, v3);
                int base = l15 * 128 + n * 32 + lg * 8;
                *(u32*)((char*)Pw + ((base) ^ swz)) = w0;
                *(u32*)((char*)Pw + ((base + 4) ^ swz)) = w1;
            }
            bf16x8 pf0 = *(const bf16x8*)((char*)Pw + ((l15 * 128 + lg * 16) ^ swz));
            bf16x8 pf1 = *(const bf16x8*)((char*)Pw + ((l15 * 128 + 64 + lg * 16) ^ swz));
            __builtin_amdgcn_s_setprio(1);
#pragma unroll
            for (int n = 0; n < 4; n++) {
                bf16x8 vf = *(const bf16x8*)(Vc + ((((n * 16 + l15) << 7) + (lg << 4)) ^ swz));
                ctxa[n] = __builtin_amdgcn_mfma_f32_16x16x32_bf16(pf0, vf, ctxa[n], 0, 0, 0);
            }
#pragma unroll
            for (int n = 0; n < 4; n++) {
                bf16x8 vf = *(const bf16x8*)(Vc + ((((n * 16 + l15) << 7) + 64 + (lg << 4)) ^ swz));
                ctxa[n] = __builtin_amdgcn_mfma_f32_16x16x32_bf16(pf1, vf, ctxa[n], 0, 0, 0);
            }
            __builtin_amdgcn_s_setprio(0);
        }
        __syncthreads();
        cur ^= 1;
    }

    float tsum = rsp;
    tsum += __shfl_xor(tsum, 16);
    tsum += __shfl_xor(tsum, 32);
    rsw[w][l15] = tsum;
    f32x4 rv = *(f32x4*)&rsw[w][lg * 4];
    const float EPS = 1e-12f, EPSN = 1e-12f / 1024.f;
    float inv[4];
#pragma unroll
    for (int r = 0; r < 4; r++) inv[r] = 1.f / (rv[r] + EPS);
    int b = bh >> 4, h = bh & 15;
#pragma unroll
    for (int n = 0; n < 4; n++) {
#pragma unroll
        for (int r = 0; r < 4; r++) {
            int qq = qb + lg * 4 + r;
            float val = (ctxa[n][r] + EPSN * vs[n]) * inv[r];
            ctx[(size_t)(b * 1024 + qq) * 1024 + h * 64 + n * 16 + l15] = f2bf(val);
        }
    }
}

// ----- fp32 fixup GEMM: q,k rows s<16 of each (b,h) exactly from fp32 X,W -----
__global__ __launch_bounds__(256) void k_qkfix(const float* __restrict__ X,
                                               const float* __restrict__ W,
                                               const float* __restrict__ bias,
                                               float* __restrict__ Qf,
                                               float* __restrict__ Kf) {
    __shared__ float red[4][8][64];
    int cb = blockIdx.x;
    int b = blockIdx.y >> 1, rh = blockIdx.y & 1;
    int tid = threadIdx.x, w = tid >> 6, lane = tid & 63;
    int col = cb * 64 + lane;

    const float* Wp = W + (size_t)(w * 256) * 3072 + col;
    const float* Xp = X + ((size_t)b * 1024 + rh * 8) * 1024 + w * 256;
    float acc[8] = {};
#pragma unroll 8
    for (int it = 0; it < 256; ++it) {
        float wv = Wp[(size_t)it * 3072];
#pragma unroll
        for (int j = 0; j < 8; j++) acc[j] += Xp[(size_t)j * 1024 + it] * wv;
    }
#pragma unroll
    for (int j = 0; j < 8; j++) red[w][j][lane] = acc[j];
    __syncthreads();

    int isK = cb >> 4, h = cb & 15;
    float* dst = isK ? Kf : Qf;
#pragma unroll
    for (int o = tid; o < 512; o += 256) {
        int j = o >> 6, c = o & 63;
        float s = red[0][j][c] + red[1][j][c] + red[2][j][c] + red[3][j][c];
        dst[((size_t)(b * 16 + h) * 16 + rh * 8 + j) * 64 + c] = s + bias[cb * 64 + c];
    }
}

// ----- fp32 fixup attention for rows q<16 of each head -----
__global__ __launch_bounds__(256) void k_attnfix(const float* __restrict__ Qf,
                                                 const float* __restrict__ Kf,
                                                 const u16* __restrict__ Vb,
                                                 const float* __restrict__ vsum,
                                                 u16* __restrict__ ctx) {
    __shared__ float ps[16][17];
    __shared__ float dens[16];
    int bh = blockIdx.x, t = threadIdx.x;
    int q = t >> 4, k = t & 15;
    const float* Qr = Qf + ((size_t)bh * 16 + q) * 64;
    const float* Kr = Kf + ((size_t)bh * 16 + k) * 64;
    float s = 0.f;
    for (int d = 0; d < 64; d++) s += Qr[d] * Kr[d];
    s *= 0.125f;
    float p = (k <= q) ? fmaxf(s, 0.f) : 0.f;
    float den = p;
    den += __shfl_xor(den, 1); den += __shfl_xor(den, 2);
    den += __shfl_xor(den, 4); den += __shfl_xor(den, 8);
    ps[q][k] = p;
    if (k == 0) dens[q] = den;
    __syncthreads();
    int d0 = (t & 15) * 4;
    float c[4] = {};
    for (int kk = 0; kk <= q; kk++) {
        float pv = ps[q][kk];
        const u16* vr = Vb + ((size_t)bh * 1024 + kk) * 64 + d0;
        c[0] += pv * bf2f(vr[0]); c[1] += pv * bf2f(vr[1]);
        c[2] += pv * bf2f(vr[2]); c[3] += pv * bf2f(vr[3]);
    }
    float inv = 1.f / (dens[q] + 1e-12f);
    const float EPSN = 1e-12f / 1024.f;
    const float* vs = vsum + bh * 64 + d0;
    int b = bh >> 4, h = bh & 15;
    u16* dst = ctx + (size_t)(b * 1024 + q) * 1024 + h * 64 + d0;
#pragma unroll
    for (int j = 0; j < 4; j++) dst[j] = f2bf((c[j] + EPSN * vs[j]) * inv);
}

extern "C" void kernel_launch(void* const* d_in, const int* in_sizes, int n_in,
                              void* d_out, int out_size, void* d_ws, size_t ws_size,
                              hipStream_t stream) {
    const float* X = (const float*)d_in[0];
    const float* Wqkv = (const float*)d_in[1];
    const float* bqkv = (const float*)d_in[2];
    const float* Wproj = (const float*)d_in[3];
    const float* bproj = (const float*)d_in[4];
    float* out = (float*)d_out;
    char* ws = (char*)d_ws;

    u16* Xb     = (u16*)(ws);
    u16* Wqkvt  = (u16*)(ws + 8388608);
    u16* Wprojt = (u16*)(ws + 14680064);
    u16* Qb     = (u16*)(ws + 16777216);
    u16* Kb     = (u16*)(ws + 25165824);
    u16* Vb     = (u16*)(ws + 33554432);
    u16* Vt     = (u16*)(ws + 41943040);
    float* vsum = (float*)(ws + 50331648);   // 16 KB
    float* Qf   = (float*)(ws + 50348032);   // 256 KB
    float* Kf   = (float*)(ws + 50610176);   // 256 KB
    float* vpart= (float*)(ws + 50872320);   // 256 KB
    u16* ctx    = Xb;  // Xb dead after GEMM1; reuse for ctx

    k_prep<<<dim3(3072), dim3(256), 0, stream>>>(X, Xb, Wqkv, Wqkvt, Wproj, Wprojt);
    k_gemm<1><<<dim3(32, 24), dim3(256), 0, stream>>>(Xb, Wqkvt, bqkv, nullptr,
                                                      Qb, Kb, Vb, Vt, vpart,
                                                      4096, 3072, 1024);
    k_vsum2<<<dim3(16), dim3(256), 0, stream>>>(vpart, vsum);
    k_qkfix<<<dim3(32, 8), dim3(256), 0, stream>>>(X, Wqkv, bqkv, Qf, Kf);
    k_attn<<<dim3(512), dim3(512), 0, stream>>>(Qb, Kb, Vt, vsum, ctx);
    k_attnfix<<<dim3(64), dim3(256), 0, stream>>>(Qf, Kf, Vb, vsum, ctx);
    k_gemmP<<<dim3(32, 16), dim3(256), 0, stream>>>(ctx, Wprojt, bproj, out);
}

// Round 11
// 116.075 us; speedup vs baseline: 1.1935x; 1.0961x over previous
//
#include <hip/hip_runtime.h>
#include <hip/hip_bf16.h>

typedef unsigned short u16;
typedef unsigned int u32;

#define AS1 __attribute__((address_space(1)))
#define AS3 __attribute__((address_space(3)))

typedef __attribute__((ext_vector_type(8))) __bf16 bf16x8;
typedef __attribute__((ext_vector_type(4))) float f32x4;
typedef __attribute__((ext_vector_type(8))) u16 u16x8;

static __device__ __forceinline__ u16 f2bf(float f) {
    u32 x = __builtin_bit_cast(u32, f);
    u32 r = (x + 0x7fffu + ((x >> 16) & 1u)) >> 16;
    return (u16)r;
}
static __device__ __forceinline__ float bf2f(u16 u) {
    u32 x = ((u32)u) << 16;
    return __builtin_bit_cast(float, x);
}
static __device__ __forceinline__ void gload_lds16(const void* g, void* l) {
    __builtin_amdgcn_global_load_lds((const AS1 u32*)g, (AS3 u32*)l, 16, 0, 0);
}
static __device__ __forceinline__ u32 cvtpk(float lo, float hi) {
    u32 r;
    asm("v_cvt_pk_bf16_f32 %0, %1, %2" : "=v"(r) : "v"(lo), "v"(hi));
    return r;
}

// ---- prep (fused): qkfix fp32 side-GEMM (blocks 0..255, launched FIRST so the
// long-loop blocks hide under the memory-bound rest) + X cast (256..2303) +
// Wqkv trans (2304..3071) + Wproj trans (3072..3327) ----
__global__ __launch_bounds__(256) void k_prep(const float* __restrict__ X,
                                              u16* __restrict__ Xb,
                                              const float* __restrict__ Wqkv,
                                              u16* __restrict__ Wqkvt,
                                              const float* __restrict__ Wproj,
                                              u16* __restrict__ Wprojt,
                                              const float* __restrict__ bqkv,
                                              float* __restrict__ Qf,
                                              float* __restrict__ Kf) {
    __shared__ u16 T[64][65];
    __shared__ float red[4][8][64];
    int bid = blockIdx.x, t = threadIdx.x;
    if (bid < 256) {
        // ---- qkfix: rows s<16 of q,k in fp32 exactly (K-split over 4 waves) ----
        int cb = bid >> 3, y = bid & 7;
        int b = y >> 1, rh = y & 1;
        int w = t >> 6, lane = t & 63;
        int col = cb * 64 + lane;
        const float* Wp = Wqkv + (size_t)(w * 256) * 3072 + col;
        const float* Xp = X + ((size_t)b * 1024 + rh * 8) * 1024 + w * 256;
        float acc[8] = {};
#pragma unroll 8
        for (int it = 0; it < 256; ++it) {
            float wv = Wp[(size_t)it * 3072];
#pragma unroll
            for (int j = 0; j < 8; j++) acc[j] += Xp[(size_t)j * 1024 + it] * wv;
        }
#pragma unroll
        for (int j = 0; j < 8; j++) red[w][j][lane] = acc[j];
        __syncthreads();
        int isK = cb >> 4, h = cb & 15;
        float* dst = isK ? Kf : Qf;
#pragma unroll
        for (int o = t; o < 512; o += 256) {
            int j = o >> 6, c = o & 63;
            float s = red[0][j][c] + red[1][j][c] + red[2][j][c] + red[3][j][c];
            dst[((size_t)(b * 16 + h) * 16 + rh * 8 + j) * 64 + c] = s + bqkv[cb * 64 + c];
        }
        return;
    }
    if (bid < 2304) {
        int i = (bid - 256) * 256 + t;
        typedef __attribute__((ext_vector_type(4))) float fx4;
        const fx4* p = (const fx4*)X;
        fx4 a = p[2 * i], bb = p[2 * i + 1];
        u16x8 o;
        o[0] = f2bf(a[0]); o[1] = f2bf(a[1]); o[2] = f2bf(a[2]); o[3] = f2bf(a[3]);
        o[4] = f2bf(bb[0]); o[5] = f2bf(bb[1]); o[6] = f2bf(bb[2]); o[7] = f2bf(bb[3]);
        *(u16x8*)(Xb + (size_t)i * 8) = o;
        return;
    }
    const float* W; u16* Wt; int N_, nt, kt;
    if (bid < 3072) {
        W = Wqkv; Wt = Wqkvt; N_ = 3072;
        int u = bid - 2304; nt = u % 48; kt = u / 48;
    } else {
        W = Wproj; Wt = Wprojt; N_ = 1024;
        int u = bid - 3072; nt = u & 15; kt = u >> 4;
    }
    int c = t & 63, r0 = t >> 6;
#pragma unroll
    for (int i = 0; i < 16; i++) {
        int k = r0 + i * 4;
        T[k][c] = f2bf(W[(size_t)(kt * 64 + k) * N_ + nt * 64 + c]);
    }
    __syncthreads();
#pragma unroll
    for (int i = 0; i < 16; i++) {
        int nn = r0 + i * 4;
        Wt[(size_t)(nt * 64 + nn) * 1024 + kt * 64 + c] = T[c][nn];
    }
}

// ---------------- bf16 MFMA GEMM (128^2, 2-phase): A[M,K] x Bt[N,K]^T ----------------
// EPI=1: QKV scatter; V-blocks write Vt (transposed) + vpart directly (vtrans fused),
// Vb only rows s<32 (attnfix needs s<16). All acc indices static (rule #20).
template <int EPI>
__global__ __launch_bounds__(256, 2) void k_gemm(
    const u16* __restrict__ A, const u16* __restrict__ Bt,
    const float* __restrict__ bias, float* __restrict__ outf,
    u16* __restrict__ Qb, u16* __restrict__ Kb, u16* __restrict__ Vb,
    u16* __restrict__ Vt, float* __restrict__ vpart,
    int Msz, int Nsz, int Ksz) {
    __shared__ u16 Al[128 * 64];
    __shared__ u16 Bl[128 * 64];
    int tid = threadIdx.x;
    int m0 = blockIdx.x * 128, n0 = blockIdx.y * 128;
    int w = tid >> 6, lane = tid & 63, l15 = lane & 15, lg = lane >> 4;
    int wr = (w >> 1) * 64, wc = (w & 1) * 64;
    f32x4 acc[4][4] = {};

    for (int k0 = 0; k0 < Ksz; k0 += 64) {
#pragma unroll
        for (int i = 0; i < 4; i++) {
            int c = i * 256 + tid;
            gload_lds16(A + (size_t)(m0 + (c >> 3)) * Ksz + k0 + (c & 7) * 8,
                        &Al[(c & ~63) * 8]);
        }
#pragma unroll
        for (int i = 0; i < 4; i++) {
            int c = i * 256 + tid;
            gload_lds16(Bt + (size_t)(n0 + (c >> 3)) * Ksz + k0 + (c & 7) * 8,
                        &Bl[(c & ~63) * 8]);
        }
        __syncthreads();
#pragma unroll
        for (int kk = 0; kk < 2; kk++) {
            bf16x8 af[4], bfr[4];
#pragma unroll
            for (int m = 0; m < 4; m++)
                af[m] = *(const bf16x8*)&Al[(wr + m * 16 + l15) * 64 + kk * 32 + lg * 8];
#pragma unroll
            for (int n = 0; n < 4; n++)
                bfr[n] = *(const bf16x8*)&Bl[(wc + n * 16 + l15) * 64 + kk * 32 + lg * 8];
#pragma unroll
            for (int m = 0; m < 4; m++)
#pragma unroll
                for (int n = 0; n < 4; n++)
                    acc[m][n] = __builtin_amdgcn_mfma_f32_16x16x32_bf16(af[m], bfr[n], acc[m][n], 0, 0, 0);
        }
        __syncthreads();
    }

    if (EPI == 0) {
#pragma unroll
        for (int n = 0; n < 4; n++) {
            int gn = n0 + wc + n * 16 + l15;
            float bv = bias[gn];
#pragma unroll
            for (int m = 0; m < 4; m++) {
                int gmb = m0 + wr + m * 16 + lg * 4;
#pragma unroll
                for (int r = 0; r < 4; r++)
                    outf[(size_t)(gmb + r) * Nsz + gn] = acc[m][n][r] + bv;
            }
        }
    } else {
        u16* T = Al;
        const int TP = 136;
        float bv[4];
#pragma unroll
        for (int n = 0; n < 4; n++) bv[n] = bias[n0 + wc + n * 16 + l15];
        int lrow = tid >> 3;           // 0..31
        int c0 = (tid & 7) << 4;       // 0..112
        int gcol = n0 + c0;
        int which = gcol >> 10, d = gcol & 1023, h = d >> 6, dd = d & 63;
        u16* dstb = which == 0 ? Qb : (which == 1 ? Kb : Vb);
        bool isV = (n0 >= 2048);
        int s0 = m0 & 1023, bq = m0 >> 10;
        int dl = tid >> 1, sh = tid & 1;  // V path: column dl 0..127, half sh
        int bhV = bq * 16 + ((n0 - 2048) >> 6) + (dl >> 6);
        float vp0 = 0.f, vp1 = 0.f;

#define EPI_CHUNK(mc)                                                              \
    {                                                                              \
        __syncthreads();                                                           \
        if (((mc) >> 1) == (w >> 1)) {                                             \
            _Pragma("unroll") for (int n = 0; n < 4; n++) {                        \
                _Pragma("unroll") for (int r = 0; r < 4; r++) {                    \
                    int lr = (lg << 2) + r;                                        \
                    T[lr * TP + wc + (n << 4) + l15] =                             \
                        f2bf(acc[2 * ((mc) & 1)][n][r] + bv[n]);                   \
                    T[(16 + lr) * TP + wc + (n << 4) + l15] =                      \
                        f2bf(acc[2 * ((mc) & 1) + 1][n][r] + bv[n]);               \
                }                                                                  \
            }                                                                      \
        }                                                                          \
        __syncthreads();                                                           \
        if (!isV) {                                                                \
            int gm = m0 + (mc) * 32 + lrow;                                        \
            int b = gm >> 10, s = gm & 1023;                                       \
            u16* dp = dstb + ((size_t)(b * 16 + h) * 1024 + s) * 64 + dd;          \
            const u16* sp = &T[lrow * TP + c0];                                    \
            *(u16x8*)dp = *(const u16x8*)sp;                                       \
            *(u16x8*)(dp + 8) = *(const u16x8*)(sp + 8);                           \
        } else {                                                                   \
            if ((mc) == 0 && s0 == 0) {                                            \
                u16* dp = dstb + ((size_t)(bq * 16 + h) * 1024 + lrow) * 64 + dd;  \
                const u16* sp = &T[lrow * TP + c0];                                \
                *(u16x8*)dp = *(const u16x8*)sp;                                   \
                *(u16x8*)(dp + 8) = *(const u16x8*)(sp + 8);                       \
            }                                                                      \
            float vls = 0.f;                                                       \
            u16x8 o0, o1;                                                          \
            _Pragma("unroll") for (int r = 0; r < 8; r++) {                        \
                u16 v = T[((sh << 4) + r) * TP + dl];                              \
                o0[r] = v; vls += bf2f(v);                                         \
            }                                                                      \
            _Pragma("unroll") for (int r = 0; r < 8; r++) {                        \
                u16 v = T[((sh << 4) + 8 + r) * TP + dl];                          \
                o1[r] = v; vls += bf2f(v);                                         \
            }                                                                      \
            vls += __shfl_xor(vls, 1);                                             \
            if ((mc) < 2) vp0 += vls; else vp1 += vls;                             \
            u16* vtp = Vt + (size_t)bhV * 65536 + (size_t)(dl & 63) * 1024 +       \
                       s0 + (mc) * 32 + (sh << 4);                                 \
            *(u16x8*)vtp = o0;                                                     \
            *(u16x8*)(vtp + 8) = o1;                                               \
        }                                                                          \
    }

        EPI_CHUNK(0) EPI_CHUNK(1) EPI_CHUNK(2) EPI_CHUNK(3)
#undef EPI_CHUNK

        if (isV && sh == 0) {
            int st0 = s0 >> 6;
            vpart[((size_t)bhV * 16 + st0) * 64 + (dl & 63)] = vp0;
            vpart[((size_t)bhV * 16 + st0 + 1) * 64 + (dl & 63)] = vp1;
        }
    }
}

// ---------- proj GEMM: 128x64 tiles (512 blocks, 2/CU), fp32 out ----------
__global__ __launch_bounds__(256, 2) void k_gemmP(
    const u16* __restrict__ A, const u16* __restrict__ Bt,
    const float* __restrict__ bias, float* __restrict__ outf) {
    __shared__ u16 Al[128 * 64];
    __shared__ u16 Bl[64 * 64];
    int tid = threadIdx.x;
    int m0 = blockIdx.x * 128, n0 = blockIdx.y * 64;
    int w = tid >> 6, lane = tid & 63, l15 = lane & 15, lg = lane >> 4;
    int wr = (w >> 1) * 64, wc = (w & 1) * 32;
    f32x4 acc[4][2] = {};

    for (int k0 = 0; k0 < 1024; k0 += 64) {
#pragma unroll
        for (int i = 0; i < 4; i++) {
            int c = i * 256 + tid;
            gload_lds16(A + (size_t)(m0 + (c >> 3)) * 1024 + k0 + (c & 7) * 8,
                        &Al[(c & ~63) * 8]);
        }
#pragma unroll
        for (int i = 0; i < 2; i++) {
            int c = i * 256 + tid;
            gload_lds16(Bt + (size_t)(n0 + (c >> 3)) * 1024 + k0 + (c & 7) * 8,
                        &Bl[(c & ~63) * 8]);
        }
        __syncthreads();
#pragma unroll
        for (int kk = 0; kk < 2; kk++) {
            bf16x8 af[4], bfr[2];
#pragma unroll
            for (int m = 0; m < 4; m++)
                af[m] = *(const bf16x8*)&Al[(wr + m * 16 + l15) * 64 + kk * 32 + lg * 8];
#pragma unroll
            for (int n = 0; n < 2; n++)
                bfr[n] = *(const bf16x8*)&Bl[(wc + n * 16 + l15) * 64 + kk * 32 + lg * 8];
#pragma unroll
            for (int m = 0; m < 4; m++)
#pragma unroll
                for (int n = 0; n < 2; n++)
                    acc[m][n] = __builtin_amdgcn_mfma_f32_16x16x32_bf16(af[m], bfr[n], acc[m][n], 0, 0, 0);
        }
        __syncthreads();
    }
#pragma unroll
    for (int n = 0; n < 2; n++) {
        int gn = n0 + wc + n * 16 + l15;
        float bv = bias[gn];
#pragma unroll
        for (int m = 0; m < 4; m++) {
            int gmb = m0 + wr + m * 16 + lg * 4;
#pragma unroll
            for (int r = 0; r < 4; r++)
                outf[(size_t)(gmb + r) * 1024 + gn] = acc[m][n][r] + bv;
        }
    }
}

// ---- attention (fused): blocks 0..511 flash attn (vsum reduced in-block from
// vpart, qb==0 wave skips its store); blocks 512..575 fp32 fixup rows q<16 ----
__global__ __launch_bounds__(512, 4) void k_attn(const u16* __restrict__ Qb,
                                                 const u16* __restrict__ Kb,
                                                 const u16* __restrict__ Vt,
                                                 const float* __restrict__ vpart,
                                                 const u16* __restrict__ Vb,
                                                 const float* __restrict__ Qf,
                                                 const float* __restrict__ Kf,
                                                 u16* __restrict__ ctx) {
    __shared__ u16 Kl[2][4096];   // [64 k-rows][128B], swizzled
    __shared__ u16 Vl[2][4096];   // [64 d-rows][128B], swizzled
    __shared__ u16 Pl[8 * 1024];  // 2KB per wave
    __shared__ float rsw[8][16];
    __shared__ float vsl[64];
    __shared__ float ps[16][17];
    __shared__ float dens[16];
    int tid = threadIdx.x, w = tid >> 6, lane = tid & 63, l15 = lane & 15, lg = lane >> 4;
    int p = blockIdx.x;

    if (p >= 512) {
        // ---------- fixup path: rows q<16 of head bhf, fp32 ----------
        int bhf = p - 512;
        if (tid < 64) {
            float s = 0.f;
            const float* pp = vpart + (size_t)bhf * 1024 + tid;
#pragma unroll
            for (int st = 0; st < 16; st++) s += pp[st * 64];
            vsl[tid] = s;
        }
        int q = tid >> 4, k = tid & 15;
        if (tid < 256) {
            const float* Qr = Qf + ((size_t)bhf * 16 + q) * 64;
            const float* Kr = Kf + ((size_t)bhf * 16 + k) * 64;
            float s = 0.f;
            for (int d = 0; d < 64; d++) s += Qr[d] * Kr[d];
            s *= 0.125f;
            float pv = (k <= q) ? fmaxf(s, 0.f) : 0.f;
            float den = pv;
            den += __shfl_xor(den, 1); den += __shfl_xor(den, 2);
            den += __shfl_xor(den, 4); den += __shfl_xor(den, 8);
            ps[q][k] = pv;
            if (k == 0) dens[q] = den;
        }
        __syncthreads();
        if (tid < 256) {
            int d0 = k * 4;
            float c[4] = {};
            for (int kk = 0; kk <= q; kk++) {
                float pv = ps[q][kk];
                const u16* vr = Vb + ((size_t)bhf * 1024 + kk) * 64 + d0;
                c[0] += pv * bf2f(vr[0]); c[1] += pv * bf2f(vr[1]);
                c[2] += pv * bf2f(vr[2]); c[3] += pv * bf2f(vr[3]);
            }
            float inv = 1.f / (dens[q] + 1e-12f);
            const float EPSN = 1e-12f / 1024.f;
            int b = bhf >> 4, h = bhf & 15;
            u16* dst = ctx + (size_t)(b * 1024 + q) * 1024 + h * 64 + d0;
#pragma unroll
            for (int j = 0; j < 4; j++) dst[j] = f2bf((c[j] + EPSN * vsl[d0 + j]) * inv);
        }
        return;
    }

    int tb = 7 - (p >> 6);        // heavy blocks dispatch first
    int bh = p & 63;              // bh%8 == p%8 -> all 8 blocks of a bh on one XCD
    int qb = tb * 128 + w * 16;
    int nkb = 2 * tb + 2;
    int klast = (qb + 15) >> 6;   // last k-block this wave participates in

    const u16* Qh = Qb + (size_t)bh * 65536;
    const u16* Kh = Kb + (size_t)bh * 65536;
    const u16* Vh = Vt + (size_t)bh * 65536;
    u16* Pw = &Pl[w * 1024];
    int swz = (l15 & 7) << 4;
    int q = qb + l15;

    bf16x8 qf[2];
#pragma unroll
    for (int kk = 0; kk < 2; kk++)
        qf[kk] = *(const bf16x8*)(Qh + (size_t)q * 64 + kk * 32 + lg * 8);

    int srow = tid >> 3, schunk = tid & 7;
    int soff = ((schunk * 16) ^ ((srow & 7) << 4)) >> 1;  // elems within row
    u16* kdst = &Kl[0][0] + w * 512;
    u16* vdst = &Vl[0][0] + w * 512;

    f32x4 ctxa[4] = {};
    float rsp = 0.f;
    int cur = 0;

    gload_lds16(Kh + (size_t)srow * 64 + soff, kdst);
    gload_lds16(Vh + (size_t)srow * 1024 + soff, vdst);
    if (tid < 64) {  // in-block vsum: same st-order as old k_vsum2 (bitwise equal)
        float s = 0.f;
        const float* pp = vpart + (size_t)bh * 1024 + tid;
#pragma unroll
        for (int st = 0; st < 16; st++) s += pp[st * 64];
        vsl[tid] = s;
    }
    __syncthreads();
    float vs[4];
#pragma unroll
    for (int n = 0; n < 4; n++) vs[n] = vsl[n * 16 + l15];

    for (int kb = 0; kb < nkb; kb++) {
        if (kb + 1 < nkb) {
            int nx = cur ^ 1;
            gload_lds16(Kh + (size_t)(((kb + 1) << 6) + srow) * 64 + soff,
                        &Kl[nx][0] + w * 512);
            gload_lds16(Vh + (size_t)srow * 1024 + ((kb + 1) << 6) + soff,
                        &Vl[nx][0] + w * 512);
        }
        if (kb <= klast) {
            bool masked = (kb == klast);
            const char* Kc = (const char*)&Kl[cur][0];
            const char* Vc = (const char*)&Vl[cur][0];
            f32x4 sc[4] = {};
            __builtin_amdgcn_s_setprio(1);
#pragma unroll
            for (int kk = 0; kk < 2; kk++)
#pragma unroll
                for (int n = 0; n < 4; n++) {
                    bf16x8 kf = *(const bf16x8*)(Kc + ((((n * 16 + l15) << 7) + (kk << 6) + (lg << 4)) ^ swz));
                    sc[n] = __builtin_amdgcn_mfma_f32_16x16x32_bf16(kf, qf[kk], sc[n], 0, 0, 0);
                }
            __builtin_amdgcn_s_setprio(0);
            int qml = q - (kb << 6) - (lg << 2);
#pragma unroll
            for (int n = 0; n < 4; n++) {
                float v0 = fmaxf(sc[n][0] * 0.125f, 0.f);
                float v1 = fmaxf(sc[n][1] * 0.125f, 0.f);
                float v2 = fmaxf(sc[n][2] * 0.125f, 0.f);
                float v3 = fmaxf(sc[n][3] * 0.125f, 0.f);
                if (masked) {
                    int c = qml - n * 16;
                    v0 = (0 <= c) ? v0 : 0.f;
                    v1 = (1 <= c) ? v1 : 0.f;
                    v2 = (2 <= c) ? v2 : 0.f;
                    v3 = (3 <= c) ? v3 : 0.f;
                }
                rsp += (v0 + v1) + (v2 + v3);
                u32 w0 = cvtpk(v0, v1), w1 = cvtpk(v2, v3);
                int base = l15 * 128 + n * 32 + lg * 8;
                *(u32*)((char*)Pw + ((base) ^ swz)) = w0;
                *(u32*)((char*)Pw + ((base + 4) ^ swz)) = w1;
            }
            bf16x8 pf0 = *(const bf16x8*)((char*)Pw + ((l15 * 128 + lg * 16) ^ swz));
            bf16x8 pf1 = *(const bf16x8*)((char*)Pw + ((l15 * 128 + 64 + lg * 16) ^ swz));
            __builtin_amdgcn_s_setprio(1);
#pragma unroll
            for (int n = 0; n < 4; n++) {
                bf16x8 vf = *(const bf16x8*)(Vc + ((((n * 16 + l15) << 7) + (lg << 4)) ^ swz));
                ctxa[n] = __builtin_amdgcn_mfma_f32_16x16x32_bf16(pf0, vf, ctxa[n], 0, 0, 0);
            }
#pragma unroll
            for (int n = 0; n < 4; n++) {
                bf16x8 vf = *(const bf16x8*)(Vc + ((((n * 16 + l15) << 7) + 64 + (lg << 4)) ^ swz));
                ctxa[n] = __builtin_amdgcn_mfma_f32_16x16x32_bf16(pf1, vf, ctxa[n], 0, 0, 0);
            }
            __builtin_amdgcn_s_setprio(0);
        }
        __syncthreads();
        cur ^= 1;
    }

    float tsum = rsp;
    tsum += __shfl_xor(tsum, 16);
    tsum += __shfl_xor(tsum, 32);
    rsw[w][l15] = tsum;
    f32x4 rv = *(f32x4*)&rsw[w][lg * 4];
    const float EPS = 1e-12f, EPSN = 1e-12f / 1024.f;
    float inv[4];
#pragma unroll
    for (int r = 0; r < 4; r++) inv[r] = 1.f / (rv[r] + EPS);
    if (qb != 0) {  // rows q<16 owned by the fixup blocks (disjoint, no race)
        int b = bh >> 4, h = bh & 15;
#pragma unroll
        for (int n = 0; n < 4; n++) {
#pragma unroll
            for (int r = 0; r < 4; r++) {
                int qq = qb + lg * 4 + r;
                float val = (ctxa[n][r] + EPSN * vs[n]) * inv[r];
                ctx[(size_t)(b * 1024 + qq) * 1024 + h * 64 + n * 16 + l15] = f2bf(val);
            }
        }
    }
}

extern "C" void kernel_launch(void* const* d_in, const int* in_sizes, int n_in,
                              void* d_out, int out_size, void* d_ws, size_t ws_size,
                              hipStream_t stream) {
    const float* X = (const float*)d_in[0];
    const float* Wqkv = (const float*)d_in[1];
    const float* bqkv = (const float*)d_in[2];
    const float* Wproj = (const float*)d_in[3];
    const float* bproj = (const float*)d_in[4];
    float* out = (float*)d_out;
    char* ws = (char*)d_ws;

    u16* Xb     = (u16*)(ws);
    u16* Wqkvt  = (u16*)(ws + 8388608);
    u16* Wprojt = (u16*)(ws + 14680064);
    u16* Qb     = (u16*)(ws + 16777216);
    u16* Kb     = (u16*)(ws + 25165824);
    u16* Vb     = (u16*)(ws + 33554432);
    u16* Vt     = (u16*)(ws + 41943040);
    float* Qf   = (float*)(ws + 50348032);   // 256 KB
    float* Kf   = (float*)(ws + 50610176);   // 256 KB
    float* vpart= (float*)(ws + 50872320);   // 256 KB
    u16* ctx    = Xb;  // Xb dead after GEMM1; reuse for ctx

    k_prep<<<dim3(3328), dim3(256), 0, stream>>>(X, Xb, Wqkv, Wqkvt, Wproj, Wprojt,
                                                 bqkv, Qf, Kf);
    k_gemm<1><<<dim3(32, 24), dim3(256), 0, stream>>>(Xb, Wqkvt, bqkv, nullptr,
                                                      Qb, Kb, Vb, Vt, vpart,
                                                      4096, 3072, 1024);
    k_attn<<<dim3(576), dim3(512), 0, stream>>>(Qb, Kb, Vt, vpart, Vb, Qf, Kf, ctx);
    k_gemmP<<<dim3(32, 16), dim3(256), 0, stream>>>(ctx, Wprojt, bproj, out);
}